// Round 4
// baseline (56.777 us; speedup 1.0000x reference)
//
#include <hip/hip_runtime.h>

// GraphUpSamplingLayer: 3-D k=1 NN argmin + batched feature gather.
// B=4, C=512, M=2048 (coarse points), N=8192 (dense points), D=3.
//
// ROUND 4 = MEASUREMENT ROUND. v2 (new structure) feeds gather; v1 (R3
// structure) runs as a dead probe into a disjoint ws region so that
// total dur_us = [v1 + gather + gap = 39.8us known] + v2_cost.
constexpr int B = 4;
constexpr int C = 512;
constexpr int M = 2048;
constexpr int N = 8192;

// ---------------------------------------------------------------------------
// v2 argmin: query-per-lane, candidate-slice-per-wave.
// Block = 512 threads = 8 waves; block owns 64 queries (one per LANE, the
// same 64 queries in every wave); wave w scans candidates [256w, 256w+256)
// via UNIFORM-address ds_read_b128 (wave broadcast: 1 LDS read per 64 pairs,
// no per-lane address math, no conflicts). Partials combined through LDS as
// packed u64 (f32bits(d)<<32)|m  -- d>=0 so float bits are order-preserving;
// low word m gives jnp.argmin first-occurrence tie-break (within-wave
// strict-< keeps smallest m; slices are ordered by w).
// ---------------------------------------------------------------------------
__global__ __launch_bounds__(512) void nn_argmin_v2(
    const float* __restrict__ pos,      // [B][N][3]
    const float* __restrict__ sub_pos,  // [B][M][3]
    int* __restrict__ idx_out)          // [B][N]
{
    __shared__ float4 sp[M];                   // 32 KB
    __shared__ unsigned long long red[8][64];  // 4 KB

    const int b  = blockIdx.x >> 7;            // 128 blocks per batch
    const int n0 = (blockIdx.x & 127) << 6;    // 64 queries per block
    const int t  = threadIdx.x;
    const int w    = t >> 6;                   // wave id 0..7
    const int lane = t & 63;

    const float* spb = sub_pos + (size_t)b * (M * 3);
    for (int i = t; i < M; i += 512)
        sp[i] = make_float4(spb[i * 3 + 0], spb[i * 3 + 1], spb[i * 3 + 2], 0.f);
    __syncthreads();

    const int n = n0 + lane;
    const float* pp = pos + ((size_t)b * N + n) * 3;
    const float px = pp[0], py = pp[1], pz = pp[2];

    float best = 1e30f;
    int bm = 0;
    const int m0 = w << 8;                     // this wave's 256-candidate slice
    #pragma unroll 8
    for (int j = 0; j < 256; ++j) {
        const float4 s = sp[m0 + j];           // uniform addr -> broadcast
        const float dx = px - s.x;
        const float dy = py - s.y;
        const float dz = pz - s.z;
        const float d = fmaf(dz, dz, fmaf(dy, dy, dx * dx));
        if (d < best) { best = d; bm = m0 + j; }  // strict <: first index wins
    }

    red[w][lane] = ((unsigned long long)__float_as_uint(best) << 32)
                   | (unsigned int)bm;
    __syncthreads();

    if (w == 0) {
        unsigned long long k = red[0][lane];
        #pragma unroll
        for (int ww = 1; ww < 8; ++ww) {
            const unsigned long long o = red[ww][lane];
            k = (o < k) ? o : k;
        }
        idx_out[(size_t)b * N + n] = (int)(unsigned int)k;
    }
}

// ---------------------------------------------------------------------------
// v1 argmin (R3 structure) -- DEAD PROBE this round: writes to ws+1MB so its
// duration is isolated in total time. Unchanged from R3.
// ---------------------------------------------------------------------------
__global__ __launch_bounds__(256) void nn_argmin_v1(
    const float* __restrict__ pos,
    const float* __restrict__ sub_pos,
    int* __restrict__ idx_out)
{
    __shared__ float4 sp[M];

    const int b  = blockIdx.x >> 8;
    const int n0 = (blockIdx.x & 255) << 5;
    const int t  = threadIdx.x;

    const float* spb = sub_pos + (size_t)b * (M * 3);
    #pragma unroll
    for (int i = t; i < M; i += 256) {
        sp[i] = make_float4(spb[i * 3 + 0], spb[i * 3 + 1], spb[i * 3 + 2], 0.f);
    }
    __syncthreads();

    const int part = t & 31;
    const int g    = t >> 5;
    const int nbase = n0 + g * 4;

    float px[4], py[4], pz[4], best[4];
    int bidx[4];
    #pragma unroll
    for (int q = 0; q < 4; ++q) {
        const float* pp = pos + ((size_t)b * N + nbase + q) * 3;
        px[q] = pp[0]; py[q] = pp[1]; pz[q] = pp[2];
        best[q] = 1e30f;
        bidx[q] = M;
    }

    constexpr int IT = M / 32;
    float4 s = sp[part];
    #pragma unroll 4
    for (int i = 0; i < IT; ++i) {
        const float4 cur = s;
        s = sp[((((i + 1) & (IT - 1)) << 5) + part)];
        const int m = (i << 5) + part;
        #pragma unroll
        for (int q = 0; q < 4; ++q) {
            const float dx = px[q] - cur.x;
            const float dy = py[q] - cur.y;
            const float dz = pz[q] - cur.z;
            const float d = dx * dx + dy * dy + dz * dz;
            if (d < best[q]) { best[q] = d; bidx[q] = m; }
        }
    }

    #pragma unroll
    for (int off = 1; off < 32; off <<= 1) {
        #pragma unroll
        for (int q = 0; q < 4; ++q) {
            const float ob = __shfl_xor(best[q], off, 64);
            const int   oi = __shfl_xor(bidx[q], off, 64);
            if (ob < best[q] || (ob == best[q] && oi < bidx[q])) {
                best[q] = ob; bidx[q] = oi;
            }
        }
    }
    if (part == 0) {
        #pragma unroll
        for (int q = 0; q < 4; ++q)
            idx_out[(size_t)b * N + nbase + q] = bidx[q];
    }
}

// ---------------------------------------------------------------------------
// Phase 2: out[b][c][n] = sub_x[b][c][idx[b][n]]  (HBM-roofline ~12us)
// ---------------------------------------------------------------------------
__global__ __launch_bounds__(256) void gather_kernel(
    const float* __restrict__ sub_x,  // [B][C][M]
    const int* __restrict__ idx,      // [B][N]
    float* __restrict__ out)          // [B][C][N]
{
    __shared__ float row[M];          // 8 KB

    const int b = blockIdx.x >> 9;    // C = 512
    const int c = blockIdx.x & 511;
    const int t = threadIdx.x;

    const float* rsrc = sub_x + ((size_t)b * C + c) * M;
    for (int i = t; i < M; i += 256) row[i] = rsrc[i];
    __syncthreads();

    const int4* iv = (const int4*)(idx + (size_t)b * N);
    float4* ov = (float4*)(out + ((size_t)b * C + c) * N);
    #pragma unroll
    for (int i = t; i < N / 4; i += 256) {
        const int4 ii = iv[i];
        float4 v;
        v.x = row[ii.x];
        v.y = row[ii.y];
        v.z = row[ii.z];
        v.w = row[ii.w];
        ov[i] = v;
    }
}

extern "C" void kernel_launch(void* const* d_in, const int* in_sizes, int n_in,
                              void* d_out, int out_size, void* d_ws, size_t ws_size,
                              hipStream_t stream) {
    const float* sub_x   = (const float*)d_in[0];  // [B][C][M]
    const float* sub_pos = (const float*)d_in[1];  // [B][M][3]
    const float* pos     = (const float*)d_in[2];  // [B][N][3]
    float* out = (float*)d_out;                    // [B][C][N]
    int* idx      = (int*)d_ws;                            // live idx (128 KB)
    int* idx_dead = (int*)((char*)d_ws + (1 << 20));       // v1 probe sink

    nn_argmin_v2<<<B * (N / 64), 512, 0, stream>>>(pos, sub_pos, idx);
    nn_argmin_v1<<<B * (N / 32), 256, 0, stream>>>(pos, sub_pos, idx_dead);
    gather_kernel<<<B * C, 256, 0, stream>>>(sub_x, idx, out);
}

// Round 5
// 36.650 us; speedup vs baseline: 1.5491x; 1.5491x over previous
//
#include <hip/hip_runtime.h>

// GraphUpSamplingLayer: 3-D k=1 NN argmin + batched feature gather.
// B=4, C=512, M=2048 (coarse points), N=8192 (dense points), D=3.
constexpr int B = 4;
constexpr int C = 512;
constexpr int M = 2048;
constexpr int N = 8192;

// ---------------------------------------------------------------------------
// v3 argmin: scalar-operand inner loop (zero LDS / zero VMEM per pair).
//
// R4 probe showed v2 (per-candidate ds_read broadcast) is LDS-issue-bound
// (~12 cyc x 4096 instr/CU ~= 20us) and v1 was latency-bound. v3 removes the
// memory system from the inner loop: candidate slices are wave-uniform, so
// readfirstlane-forcing the slice base makes the compiler emit s_load into
// SGPRs (sub_pos slice is K$/L2-resident). Each distance op reads exactly one
// SGPR (ISA limit OK).
//
// Block = 1024 threads = 16 waves; 64 queries/block (one per LANE, same in
// every wave); wave w scans candidates [128w, 128w+128). 512 blocks ->
// 2 blocks/CU = 32 waves/CU = 8 waves/SIMD (full occupancy).
// 4 independent min-chains per lane break the cmp->cndmask serial chain.
// Tie-break = jnp.argmin first-occurrence: strict < within a chain (earliest
// c in that chain), lexicographic (d, m) merge across chains, packed-u64
// (f32bits(d)<<32 | m) min across waves (d >= 0 so float bits order-preserve).
// ---------------------------------------------------------------------------
__global__ __launch_bounds__(1024) void nn_argmin_v3(
    const float* __restrict__ pos,      // [B][N][3]
    const float* __restrict__ sub_pos,  // [B][M][3]
    int* __restrict__ idx_out)          // [B][N]
{
    __shared__ unsigned long long red[16][64];   // 8 KB

    const int b  = blockIdx.x >> 7;              // 128 blocks per batch
    const int n0 = (blockIdx.x & 127) << 6;      // 64 queries per block
    const int t  = threadIdx.x;
    const int w    = t >> 6;                     // wave id 0..15
    const int lane = t & 63;

    // Wave-uniform slice base, forced into an SGPR so candidate loads
    // scalarize (s_load) instead of going through VMEM/LDS.
    const int wu = __builtin_amdgcn_readfirstlane(w);
    const int m0 = wu << 7;                      // 128-candidate slice
    const float* __restrict__ sl = sub_pos + (size_t)b * (M * 3) + (size_t)m0 * 3;

    const int n = n0 + lane;
    const float* pp = pos + ((size_t)b * N + n) * 3;
    const float px = pp[0], py = pp[1], pz = pp[2];

    float best[4] = {1e30f, 1e30f, 1e30f, 1e30f};
    int   bm[4]   = {0, 0, 0, 0};

    // 8 chunks of 16 candidates; chunk = 48 contiguous floats -> s_load_x16 x3.
    for (int j0 = 0; j0 < 128; j0 += 16) {
        #pragma unroll
        for (int j = 0; j < 16; ++j) {           // j compile-time => static k
            const int c = j0 + j;
            const float sx = sl[c * 3 + 0];
            const float sy = sl[c * 3 + 1];
            const float sz = sl[c * 3 + 2];
            const float dx = px - sx;
            const float dy = py - sy;
            const float dz = pz - sz;
            const float d = fmaf(dz, dz, fmaf(dy, dy, dx * dx));
            const int k = j & 3;                 // 4 independent chains (ILP)
            if (d < best[k]) { best[k] = d; bm[k] = m0 + c; }  // strict <
        }
    }

    // Merge the 4 chains: lexicographic (d, m) min == first-occurrence.
    unsigned long long kb = ((unsigned long long)__float_as_uint(best[0]) << 32)
                            | (unsigned int)bm[0];
    #pragma unroll
    for (int k = 1; k < 4; ++k) {
        const unsigned long long o =
            ((unsigned long long)__float_as_uint(best[k]) << 32)
            | (unsigned int)bm[k];
        kb = (o < kb) ? o : kb;
    }

    red[w][lane] = kb;
    __syncthreads();

    if (w == 0) {
        unsigned long long kmin = red[0][lane];
        #pragma unroll
        for (int ww = 1; ww < 16; ++ww) {
            const unsigned long long o = red[ww][lane];
            kmin = (o < kmin) ? o : kmin;
        }
        idx_out[(size_t)b * N + n] = (int)(unsigned int)kmin;
    }
}

// ---------------------------------------------------------------------------
// Phase 2: out[b][c][n] = sub_x[b][c][idx[b][n]]
// At/above the D2D copy ceiling already (80 MB HBM in ~11.9us ~= 6.8 TB/s
// effective); unchanged.
// ---------------------------------------------------------------------------
__global__ __launch_bounds__(256) void gather_kernel(
    const float* __restrict__ sub_x,  // [B][C][M]
    const int* __restrict__ idx,      // [B][N]
    float* __restrict__ out)          // [B][C][N]
{
    __shared__ float row[M];          // 8 KB

    const int b = blockIdx.x >> 9;    // C = 512
    const int c = blockIdx.x & 511;
    const int t = threadIdx.x;

    const float* rsrc = sub_x + ((size_t)b * C + c) * M;
    for (int i = t; i < M; i += 256) row[i] = rsrc[i];
    __syncthreads();

    const int4* iv = (const int4*)(idx + (size_t)b * N);
    float4* ov = (float4*)(out + ((size_t)b * C + c) * N);
    #pragma unroll
    for (int i = t; i < N / 4; i += 256) {
        const int4 ii = iv[i];
        float4 v;
        v.x = row[ii.x];
        v.y = row[ii.y];
        v.z = row[ii.z];
        v.w = row[ii.w];
        ov[i] = v;
    }
}

extern "C" void kernel_launch(void* const* d_in, const int* in_sizes, int n_in,
                              void* d_out, int out_size, void* d_ws, size_t ws_size,
                              hipStream_t stream) {
    const float* sub_x   = (const float*)d_in[0];  // [B][C][M]
    const float* sub_pos = (const float*)d_in[1];  // [B][M][3]
    const float* pos     = (const float*)d_in[2];  // [B][N][3]
    float* out = (float*)d_out;                    // [B][C][N]
    int* idx = (int*)d_ws;                         // B*N*4 = 128 KB scratch

    nn_argmin_v3<<<B * (N / 64), 1024, 0, stream>>>(pos, sub_pos, idx);
    gather_kernel<<<B * C, 256, 0, stream>>>(sub_x, idx, out);
}